// Round 1
// baseline (162.662 us; speedup 1.0000x reference)
//
#include <hip/hip_runtime.h>
#include <hip/hip_bf16.h>

#define NODES 8192
#define INF_ 256
#define OUTF 128
#define LRALPHA 0.02f

typedef __bf16 bf16;
typedef bf16 bf16x4 __attribute__((ext_vector_type(4)));
typedef bf16 bf16x8 __attribute__((ext_vector_type(8)));
typedef float f32x4 __attribute__((ext_vector_type(4)));
typedef float f32x16 __attribute__((ext_vector_type(16)));
typedef int i32x4 __attribute__((ext_vector_type(4)));

// ---------------- Kernel 1: Wh = x@W1 + b1 (f32), produce WhbT(bf16) + factored exp arrays ----
__global__ __launch_bounds__(256) void gat_prep_r1(
    const float* __restrict__ x, const float* __restrict__ W1,
    const float* __restrict__ b1, const float* __restrict__ a,
    const float* __restrict__ b_att,
    bf16* __restrict__ WhbT, float* __restrict__ fsb, float* __restrict__ E1,
    float* __restrict__ E2, float* __restrict__ fd, float* __restrict__ F1,
    float* __restrict__ F2)
{
    __shared__ float xsT[64][36];    // [k][row], padded
    __shared__ float ws1[64][132];   // [k][col], padded (132*4=528B row stride, 16B aligned)
    __shared__ float wh[32][128];    // Wh tile f32

    const int t = threadIdx.x;
    const int rbase = blockIdx.x * 32;
    const int tr = t >> 5;   // 0..7  -> rows tr*4..+3
    const int tc = t & 31;   // 0..31 -> cols tc*4..+3

    f32x4 acc[4];
    f32x4 bias = *(const f32x4*)&b1[tc * 4];
#pragma unroll
    for (int i = 0; i < 4; ++i) acc[i] = bias;

    for (int kt = 0; kt < 4; ++kt) {
        const int kb = kt * 64;
        {   // stage x tile transposed: xsT[k][r] = x[rbase+r][kb+k]
            int r = t >> 3;            // 0..31
            int kq = (t & 7) * 8;      // 0..56
            f32x4 v0 = *(const f32x4*)&x[(size_t)(rbase + r) * INF_ + kb + kq];
            f32x4 v1 = *(const f32x4*)&x[(size_t)(rbase + r) * INF_ + kb + kq + 4];
#pragma unroll
            for (int i = 0; i < 4; ++i) xsT[kq + i][r] = v0[i];
#pragma unroll
            for (int i = 0; i < 4; ++i) xsT[kq + 4 + i][r] = v1[i];
        }
        {   // stage W1 tile: ws1[k][c] = W1[kb+k][c]
            int kr = t >> 2;           // 0..63
            int cq = (t & 3) * 32;
#pragma unroll
            for (int i = 0; i < 8; ++i) {
                f32x4 v = *(const f32x4*)&W1[(size_t)(kb + kr) * OUTF + cq + i * 4];
                *(f32x4*)&ws1[kr][cq + i * 4] = v;
            }
        }
        __syncthreads();
        for (int kk = 0; kk < 64; ++kk) {
            f32x4 xa = *(const f32x4*)&xsT[kk][tr * 4];
            f32x4 wb = *(const f32x4*)&ws1[kk][tc * 4];
#pragma unroll
            for (int i = 0; i < 4; ++i)
#pragma unroll
                for (int j = 0; j < 4; ++j)
                    acc[i][j] += xa[i] * wb[j];
        }
        __syncthreads();
    }

#pragma unroll
    for (int i = 0; i < 4; ++i)
        *(f32x4*)&wh[tr * 4 + i][tc * 4] = acc[i];
    __syncthreads();

    // per-row dots with 'a' halves + factored exps (threads 0..31 <-> rows)
    if (t < 32) {
        float s1 = 0.f, s2 = 0.f;
        for (int c = 0; c < OUTF; ++c) {
            float v = wh[t][c];
            s1 += v * a[c];
            s2 += v * a[OUTF + c];
        }
        float fsv = s1 + b_att[0];
        int r = rbase + t;
        fsb[r] = fsv;
        E1[r] = expf(fsv);
        E2[r] = expf(LRALPHA * fsv);
        fd[r] = s2;
        F1[r] = expf(s2);
        F2[r] = expf(LRALPHA * s2);
    }

    // WhbT[c][node] = bf16(Wh[node][c]) ; thread -> c = t>>1, 16 consecutive nodes
    {
        int c = t >> 1;
        int rr = (t & 1) * 16;
        bf16x8 b0, b1v;
#pragma unroll
        for (int i = 0; i < 8; ++i) b0[i] = (bf16)wh[rr + i][c];
#pragma unroll
        for (int i = 0; i < 8; ++i) b1v[i] = (bf16)wh[rr + 8 + i][c];
        *(bf16x8*)&WhbT[(size_t)c * NODES + rbase + rr] = b0;
        *(bf16x8*)&WhbT[(size_t)c * NODES + rbase + rr + 8] = b1v;
    }
}

// ---------------- Kernel 2: fused masked softmax + PV (bf16 MFMA) + elu ----------------
// block: 512 thr (8 waves), owns 32 rows; waves split 8192 cols 8-way (1024 each).
__global__ __launch_bounds__(512) void gat_attn_r1(
    const int* __restrict__ adj,
    const bf16* __restrict__ WhbT,
    const float* __restrict__ fsb, const float* __restrict__ E1,
    const float* __restrict__ E2, const float* __restrict__ fd,
    const float* __restrict__ F1, const float* __restrict__ F2,
    float* __restrict__ out)
{
    extern __shared__ char smem[];
    // layout: [0,32768) wave-private w tiles (8 x 4KB, XOR-swizzled)
    //         [32768, 32768+7*16384) acc reduction zones (waves 1..7)
    //         [147456, 147456+1024) den partials denred[8][32]
    const int tid = threadIdx.x;
    const int wave = tid >> 6;
    const int lane = tid & 63;
    const int rbase = blockIdx.x * 32;

    char* wzone = smem + wave * 4096;
    float* red = (float*)(smem + 32768);
    float* denred = (float*)(smem + 32768 + 7 * 16384);

    const int lg = lane >> 4;    // 0..3 : row subgroup for adj/w compute
    const int lj = lane & 15;    // 0..15: j subgroup
    const int arow = lane & 31;  // MFMA A row / D col
    const int ag = lane >> 5;    // 0..1 : MFMA k lane-group

    // row constants for rows rbase + 4k + lg
    float fsbv[8], e1v[8], e2v[8];
#pragma unroll
    for (int k = 0; k < 8; ++k) {
        int r = rbase + 4 * k + lg;
        fsbv[k] = fsb[r];
        e1v[k] = E1[r];
        e2v[k] = E2[r];
    }

    f32x16 acc[4];
#pragma unroll
    for (int t = 0; t < 4; ++t)
#pragma unroll
        for (int i = 0; i < 16; ++i) acc[t][i] = 0.f;

    float den[8];
#pragma unroll
    for (int k = 0; k < 8; ++k) den[k] = 0.f;

    const int jw0 = wave * (NODES / 8);

    for (int rd = 0; rd < 16; ++rd) {
        const int jb = jw0 + rd * 64;

        i32x4 av[8];
#pragma unroll
        for (int k = 0; k < 8; ++k)
            av[k] = *(const i32x4*)&adj[(size_t)(rbase + 4 * k + lg) * NODES + jb + 4 * lj];
        f32x4 fdv = *(const f32x4*)&fd[jb + 4 * lj];
        f32x4 f1v = *(const f32x4*)&F1[jb + 4 * lj];
        f32x4 f2v = *(const f32x4*)&F2[jb + 4 * lj];

        // compute weights, accumulate den, write bf16 w-tile to swizzled LDS
#pragma unroll
        for (int k = 0; k < 8; ++k) {
            const int row = 4 * k + lg;
            bf16x4 wb;
#pragma unroll
            for (int jj = 0; jj < 4; ++jj) {
                float s = fsbv[k] + fdv[jj];
                bool pos = s > 0.f;
                float wv = (pos ? e1v[k] : e2v[k]) * (pos ? f1v[jj] : f2v[jj]);
                wv = av[k][jj] ? wv : 0.f;
                den[k] += wv;
                wb[jj] = (bf16)wv;
            }
            const int off = (row * 128 + lj * 8) ^ ((row & 7) << 4);
            *(bf16x4*)(wzone + off) = wb;
        }

        // MFMA: D[32 rows][128 cols] += w[32][64] * Whb[64][128], k-chunks of 16
#pragma unroll
        for (int m = 0; m < 4; ++m) {
            const int aoff = (arow * 128 + m * 32 + ag * 16) ^ ((arow & 7) << 4);
            bf16x8 af = *(const bf16x8*)(wzone + aoff);
#pragma unroll
            for (int t = 0; t < 4; ++t) {
                bf16x8 bfr = *(const bf16x8*)&WhbT[(size_t)(32 * t + arow) * NODES + jb + 16 * m + 8 * ag];
                acc[t] = __builtin_amdgcn_mfma_f32_32x32x16_bf16(af, bfr, acc[t], 0, 0, 0);
            }
        }
    }

    // den: sum over the 16 j-lanes (bits 0..3), deterministic
#pragma unroll
    for (int k = 0; k < 8; ++k) {
        float v = den[k];
        v += __shfl_xor(v, 1);
        v += __shfl_xor(v, 2);
        v += __shfl_xor(v, 4);
        v += __shfl_xor(v, 8);
        den[k] = v;
    }
    if (lj == 0) {
#pragma unroll
        for (int k = 0; k < 8; ++k)
            denred[wave * 32 + 4 * k + lg] = den[k];
    }

    // acc: waves 1..7 dump to LDS zones (flat, same lane mapping as reader)
    if (wave > 0) {
        float* z = red + (size_t)(wave - 1) * 4096 + lane * 64;
#pragma unroll
        for (int t = 0; t < 4; ++t)
            *(f32x16*)(z + 16 * t) = acc[t];
    }
    __syncthreads();

    if (wave == 0) {
#pragma unroll
        for (int w = 0; w < 7; ++w) {
            const float* z = red + (size_t)w * 4096 + lane * 64;
#pragma unroll
            for (int t = 0; t < 4; ++t) {
                f32x16 v = *(const f32x16*)(z + 16 * t);
                acc[t] += v;
            }
        }
#pragma unroll
        for (int rg = 0; rg < 16; ++rg) {
            const int row = (rg & 3) + 8 * (rg >> 2) + 4 * ag;  // verified C/D mapping (m74/m101)
            float dsum = 0.f;
#pragma unroll
            for (int w = 0; w < 8; ++w) dsum += denred[w * 32 + row];
#pragma unroll
            for (int t = 0; t < 4; ++t) {
                float v = acc[t][rg] / dsum;
                v = v > 0.f ? v : expm1f(v);
                out[(size_t)(rbase + row) * OUTF + 32 * t + arow] = v;
            }
        }
    }
}

extern "C" void kernel_launch(void* const* d_in, const int* in_sizes, int n_in,
                              void* d_out, int out_size, void* d_ws, size_t ws_size,
                              hipStream_t stream) {
    const float* x     = (const float*)d_in[0];
    const int*   adj   = (const int*)d_in[1];
    const float* W1    = (const float*)d_in[2];
    const float* b1    = (const float*)d_in[3];
    const float* a     = (const float*)d_in[4];
    const float* b_att = (const float*)d_in[5];
    float* out = (float*)d_out;

    char* ws = (char*)d_ws;
    bf16* WhbT = (bf16*)ws;                                   // 2 MB
    float* fsb = (float*)(ws + (size_t)2 * 1024 * 1024);
    float* E1 = fsb + NODES;
    float* E2 = E1 + NODES;
    float* fd = E2 + NODES;
    float* F1 = fd + NODES;
    float* F2 = F1 + NODES;

    hipLaunchKernelGGL(gat_prep_r1, dim3(NODES / 32), dim3(256), 0, stream,
                       x, W1, b1, a, b_att, WhbT, fsb, E1, E2, fd, F1, F2);

    const size_t smem2 = 32768 + 7 * 16384 + 1024;  // 148480 B
    hipLaunchKernelGGL(gat_attn_r1, dim3(NODES / 32), dim3(512), smem2, stream,
                       adj, WhbT, fsb, E1, E2, fd, F1, F2, out);
}

// Round 2
// 137.999 us; speedup vs baseline: 1.1787x; 1.1787x over previous
//
#include <hip/hip_runtime.h>
#include <hip/hip_bf16.h>

#define NODES 8192
#define INF_ 256
#define OUTF 128
#define LRALPHA 0.02f

typedef __bf16 bf16;
typedef bf16 bf16x4 __attribute__((ext_vector_type(4)));
typedef bf16 bf16x8 __attribute__((ext_vector_type(8)));
typedef float f32x4 __attribute__((ext_vector_type(4)));
typedef float f32x16 __attribute__((ext_vector_type(16)));
typedef int i32x4 __attribute__((ext_vector_type(4)));

// ---------------- Kernel 1: Wh = x@W1 + b1 (f32), produce WhbT(bf16) + factored exp arrays ----
__global__ __launch_bounds__(256) void gat_prep_r2(
    const float* __restrict__ x, const float* __restrict__ W1,
    const float* __restrict__ b1, const float* __restrict__ a,
    const float* __restrict__ b_att,
    bf16* __restrict__ WhbT, float* __restrict__ fsb, float* __restrict__ E1,
    float* __restrict__ E2, float* __restrict__ fd, float* __restrict__ F1,
    float* __restrict__ F2)
{
    __shared__ float xsT[64][36];    // [k][row], padded
    __shared__ float ws1[64][132];   // [k][col], padded
    __shared__ float wh[32][128];    // Wh tile f32

    const int t = threadIdx.x;
    const int rbase = blockIdx.x * 32;
    const int tr = t >> 5;   // 0..7  -> rows tr*4..+3
    const int tc = t & 31;   // 0..31 -> cols tc*4..+3

    f32x4 acc[4];
    f32x4 bias = *(const f32x4*)&b1[tc * 4];
#pragma unroll
    for (int i = 0; i < 4; ++i) acc[i] = bias;

    for (int kt = 0; kt < 4; ++kt) {
        const int kb = kt * 64;
        {   // stage x tile transposed: xsT[k][r] = x[rbase+r][kb+k]
            int r = t >> 3;            // 0..31
            int kq = (t & 7) * 8;      // 0..56
            f32x4 v0 = *(const f32x4*)&x[(size_t)(rbase + r) * INF_ + kb + kq];
            f32x4 v1 = *(const f32x4*)&x[(size_t)(rbase + r) * INF_ + kb + kq + 4];
#pragma unroll
            for (int i = 0; i < 4; ++i) xsT[kq + i][r] = v0[i];
#pragma unroll
            for (int i = 0; i < 4; ++i) xsT[kq + 4 + i][r] = v1[i];
        }
        {   // stage W1 tile: ws1[k][c] = W1[kb+k][c]
            int kr = t >> 2;           // 0..63
            int cq = (t & 3) * 32;
#pragma unroll
            for (int i = 0; i < 8; ++i) {
                f32x4 v = *(const f32x4*)&W1[(size_t)(kb + kr) * OUTF + cq + i * 4];
                *(f32x4*)&ws1[kr][cq + i * 4] = v;
            }
        }
        __syncthreads();
        for (int kk = 0; kk < 64; ++kk) {
            f32x4 xa = *(const f32x4*)&xsT[kk][tr * 4];
            f32x4 wb = *(const f32x4*)&ws1[kk][tc * 4];
#pragma unroll
            for (int i = 0; i < 4; ++i)
#pragma unroll
                for (int j = 0; j < 4; ++j)
                    acc[i][j] += xa[i] * wb[j];
        }
        __syncthreads();
    }

#pragma unroll
    for (int i = 0; i < 4; ++i)
        *(f32x4*)&wh[tr * 4 + i][tc * 4] = acc[i];
    __syncthreads();

    if (t < 32) {
        float s1 = 0.f, s2 = 0.f;
        for (int c = 0; c < OUTF; ++c) {
            float v = wh[t][c];
            s1 += v * a[c];
            s2 += v * a[OUTF + c];
        }
        float fsv = s1 + b_att[0];
        int r = rbase + t;
        fsb[r] = fsv;
        E1[r] = expf(fsv);
        E2[r] = expf(LRALPHA * fsv);
        fd[r] = s2;
        F1[r] = expf(s2);
        F2[r] = expf(LRALPHA * s2);
    }

    {   // WhbT[c][node] = bf16(Wh[node][c])
        int c = t >> 1;
        int rr = (t & 1) * 16;
        bf16x8 b0, b1v;
#pragma unroll
        for (int i = 0; i < 8; ++i) b0[i] = (bf16)wh[rr + i][c];
#pragma unroll
        for (int i = 0; i < 8; ++i) b1v[i] = (bf16)wh[rr + 8 + i][c];
        *(bf16x8*)&WhbT[(size_t)c * NODES + rbase + rr] = b0;
        *(bf16x8*)&WhbT[(size_t)c * NODES + rbase + rr + 8] = b1v;
    }
}

// ---------------- Kernel 2: fused masked softmax + PV (bf16 MFMA) + elu ----------------
// 1024 thr = 16 waves = 4 jgroups x 4 t-tiles. Block owns 32 rows; jgroup owns 2048 cols.
// w[32][64] bf16 tile shared per jgroup via double-buffered LDS; 1 barrier/phase
// (lgkmcnt-only, keeps adj prefetch in flight). acc per wave = one 32x32 f32 tile.
#define SOFT_BAR() do { asm volatile("s_waitcnt lgkmcnt(0)" ::: "memory"); \
                        __builtin_amdgcn_s_barrier(); } while (0)

__global__ __launch_bounds__(1024, 4) void gat_attn_r2(
    const int* __restrict__ adj,
    const bf16* __restrict__ WhbT,
    const float* __restrict__ fsb, const float* __restrict__ E1,
    const float* __restrict__ E2, const float* __restrict__ fd,
    const float* __restrict__ F1, const float* __restrict__ F2,
    float* __restrict__ out)
{
    extern __shared__ char smem[];
    // [0, 32768)        : 4 jgroups x 2 w-buffers x 4KB (aliased by epilogue zones [0,49152))
    // [49152, 49664)    : denred[4][32] f32
    const int tid = threadIdx.x;
    const int wv = tid >> 6;       // 0..15
    const int lane = tid & 63;
    const int jg = wv >> 2;        // 0..3 : column group
    const int tt = wv & 3;         // 0..3 : output col tile / weight row group
    const int rbase = blockIdx.x * 32;

    char* wbufA = smem + (jg * 2) * 4096;
    char* wbufB = smem + (jg * 2 + 1) * 4096;
    float* denred = (float*)(smem + 49152);

    const int r8 = lane >> 3;          // 0..7
    const int c8 = lane & 7;           // 0..7
    const int wrow = tt * 8 + r8;      // 0..31 : weight row this lane computes
    const int arow = lane & 31;        // MFMA A-row / B-col / D-col
    const int ag = lane >> 5;          // 0..1  : k lane-group

    const int gr = rbase + wrow;
    const float fsbv = fsb[gr];
    const float e1v = E1[gr];
    const float e2v = E2[gr];

    f32x16 acc;
#pragma unroll
    for (int i = 0; i < 16; ++i) acc[i] = 0.f;
    float den = 0.f;

    const int jw0 = jg * (NODES / 4);
    const size_t adj_row = (size_t)gr * NODES;
    const size_t whb_row = (size_t)(32 * tt + arow) * NODES;

    // weights for columns [jb, jb+64) -> bf16 tile row wrow in buf (XOR-swizzled)
    auto compute_w = [&](char* buf, int jb, i32x4 a0, i32x4 a1) {
        f32x4 fd0 = *(const f32x4*)&fd[jb + c8 * 8];
        f32x4 fd1 = *(const f32x4*)&fd[jb + c8 * 8 + 4];
        f32x4 g10 = *(const f32x4*)&F1[jb + c8 * 8];
        f32x4 g11 = *(const f32x4*)&F1[jb + c8 * 8 + 4];
        f32x4 g20 = *(const f32x4*)&F2[jb + c8 * 8];
        f32x4 g21 = *(const f32x4*)&F2[jb + c8 * 8 + 4];
        bf16x8 wb;
#pragma unroll
        for (int jj = 0; jj < 4; ++jj) {
            float s = fsbv + fd0[jj];
            bool pos = s > 0.f;
            float w = (pos ? e1v : e2v) * (pos ? g10[jj] : g20[jj]);
            w = a0[jj] ? w : 0.f;
            den += w;
            wb[jj] = (bf16)w;
        }
#pragma unroll
        for (int jj = 0; jj < 4; ++jj) {
            float s = fsbv + fd1[jj];
            bool pos = s > 0.f;
            float w = (pos ? e1v : e2v) * (pos ? g11[jj] : g21[jj]);
            w = a1[jj] ? w : 0.f;
            den += w;
            wb[4 + jj] = (bf16)w;
        }
        const int off = (wrow * 128 + c8 * 16) ^ ((wrow & 7) << 4);
        *(bf16x8*)(buf + off) = wb;
    };

    auto do_mfma = [&](const char* buf, int jb) {
        bf16x8 bfr[4];
#pragma unroll
        for (int m = 0; m < 4; ++m)
            bfr[m] = *(const bf16x8*)&WhbT[whb_row + jb + 16 * m + 8 * ag];
        bf16x8 af[4];
#pragma unroll
        for (int m = 0; m < 4; ++m) {
            const int aoff = (arow * 128 + m * 32 + ag * 16) ^ ((arow & 7) << 4);
            af[m] = *(const bf16x8*)(buf + aoff);
        }
#pragma unroll
        for (int m = 0; m < 4; ++m)
            acc = __builtin_amdgcn_mfma_f32_32x32x16_bf16(af[m], bfr[m], acc, 0, 0, 0);
    };

    // prologue: phase 0 weights into bufA; prefetch phase-1 adj
    i32x4 a0 = *(const i32x4*)&adj[adj_row + jw0 + c8 * 8];
    i32x4 a1 = *(const i32x4*)&adj[adj_row + jw0 + c8 * 8 + 4];
    i32x4 b0 = *(const i32x4*)&adj[adj_row + jw0 + 64 + c8 * 8];
    i32x4 b1 = *(const i32x4*)&adj[adj_row + jw0 + 64 + c8 * 8 + 4];
    compute_w(wbufA, jw0, a0, a1);
    SOFT_BAR();

    char* cur = wbufA;
    char* nxt = wbufB;
#pragma unroll 2
    for (int p = 0; p < 32; ++p) {
        const int jb = jw0 + p * 64;
        // depth-2 adj prefetch (clamped at tail; values unused then)
        const int pc = (p + 2 <= 31) ? (p + 2) : 31;
        i32x4 n0 = *(const i32x4*)&adj[adj_row + jw0 + pc * 64 + c8 * 8];
        i32x4 n1 = *(const i32x4*)&adj[adj_row + jw0 + pc * 64 + c8 * 8 + 4];
        if (p < 31) compute_w(nxt, jb + 64, b0, b1);   // weights for next phase
        do_mfma(cur, jb);                               // MFMA on current buffer
        SOFT_BAR();
        b0 = n0; b1 = n1;
        char* tmp = cur; cur = nxt; nxt = tmp;
    }

    // den: reduce over the 8 column-lanes (bits 0..2)
    den += __shfl_xor(den, 1);
    den += __shfl_xor(den, 2);
    den += __shfl_xor(den, 4);
    if (c8 == 0) denred[jg * 32 + wrow] = den;

    // partial acc tiles from jgroups 1..3 -> LDS zones (alias w-buffers, all dead)
    if (jg > 0) {
        float* z = (float*)(smem + (size_t)((jg - 1) * 4 + tt) * 4096) + lane * 16;
        *(f32x16*)z = acc;
    }
    __syncthreads();

    if (jg == 0) {
#pragma unroll
        for (int q = 0; q < 3; ++q) {
            const float* z = (const float*)(smem + (size_t)(q * 4 + tt) * 4096) + lane * 16;
            f32x16 v = *(const f32x16*)z;
#pragma unroll
            for (int i = 0; i < 16; ++i) acc[i] += v[i];
        }
#pragma unroll
        for (int rg = 0; rg < 16; ++rg) {
            const int row = (rg & 3) + 8 * (rg >> 2) + 4 * ag;  // verified C/D mapping
            float ds = denred[row] + denred[32 + row] + denred[64 + row] + denred[96 + row];
            float v = acc[rg] / ds;
            v = v > 0.f ? v : expm1f(v);
            out[(size_t)(rbase + row) * OUTF + 32 * tt + arow] = v;
        }
    }
}

extern "C" void kernel_launch(void* const* d_in, const int* in_sizes, int n_in,
                              void* d_out, int out_size, void* d_ws, size_t ws_size,
                              hipStream_t stream) {
    const float* x     = (const float*)d_in[0];
    const int*   adj   = (const int*)d_in[1];
    const float* W1    = (const float*)d_in[2];
    const float* b1    = (const float*)d_in[3];
    const float* a     = (const float*)d_in[4];
    const float* b_att = (const float*)d_in[5];
    float* out = (float*)d_out;

    char* ws = (char*)d_ws;
    bf16* WhbT = (bf16*)ws;                                   // 2 MB
    float* fsb = (float*)(ws + (size_t)2 * 1024 * 1024);
    float* E1 = fsb + NODES;
    float* E2 = E1 + NODES;
    float* fd = E2 + NODES;
    float* F1 = fd + NODES;
    float* F2 = F1 + NODES;

    hipLaunchKernelGGL(gat_prep_r2, dim3(NODES / 32), dim3(256), 0, stream,
                       x, W1, b1, a, b_att, WhbT, fsb, E1, E2, fd, F1, F2);

    const size_t smem2 = 49152 + 512;  // w-buffers/reduction zones + denred
    hipLaunchKernelGGL(gat_attn_r2, dim3(NODES / 32), dim3(1024), smem2, stream,
                       adj, WhbT, fsb, E1, E2, fd, F1, F2, out);
}

// Round 3
// 120.098 us; speedup vs baseline: 1.3544x; 1.1491x over previous
//
#include <hip/hip_runtime.h>
#include <hip/hip_bf16.h>

#define NODES 8192
#define INF_ 256
#define OUTF 128
#define LRALPHA 0.02f

typedef __bf16 bf16;
typedef bf16 bf16x4 __attribute__((ext_vector_type(4)));
typedef bf16 bf16x8 __attribute__((ext_vector_type(8)));
typedef float f32x4 __attribute__((ext_vector_type(4)));
typedef float f32x16 __attribute__((ext_vector_type(16)));
typedef int i32x4 __attribute__((ext_vector_type(4)));

// ---------------- Kernel 1: Wh = x@W1 + b1 (f32), produce WhbT(bf16) + factored exp arrays ----
__global__ __launch_bounds__(256) void gat_prep_r3(
    const float* __restrict__ x, const float* __restrict__ W1,
    const float* __restrict__ b1, const float* __restrict__ a,
    const float* __restrict__ b_att,
    bf16* __restrict__ WhbT, float* __restrict__ fsb, float* __restrict__ E1,
    float* __restrict__ E2, float* __restrict__ fd, float* __restrict__ F1,
    float* __restrict__ F2)
{
    __shared__ float xsT[64][36];    // [k][row], padded
    __shared__ float ws1[64][132];   // [k][col], padded
    __shared__ float wh[32][128];    // Wh tile f32

    const int t = threadIdx.x;
    const int rbase = blockIdx.x * 32;
    const int tr = t >> 5;   // 0..7  -> rows tr*4..+3
    const int tc = t & 31;   // 0..31 -> cols tc*4..+3

    f32x4 acc[4];
    f32x4 bias = *(const f32x4*)&b1[tc * 4];
#pragma unroll
    for (int i = 0; i < 4; ++i) acc[i] = bias;

    for (int kt = 0; kt < 4; ++kt) {
        const int kb = kt * 64;
        {   // stage x tile transposed: xsT[k][r] = x[rbase+r][kb+k]
            int r = t >> 3;            // 0..31
            int kq = (t & 7) * 8;      // 0..56
            f32x4 v0 = *(const f32x4*)&x[(size_t)(rbase + r) * INF_ + kb + kq];
            f32x4 v1 = *(const f32x4*)&x[(size_t)(rbase + r) * INF_ + kb + kq + 4];
#pragma unroll
            for (int i = 0; i < 4; ++i) xsT[kq + i][r] = v0[i];
#pragma unroll
            for (int i = 0; i < 4; ++i) xsT[kq + 4 + i][r] = v1[i];
        }
        {   // stage W1 tile: ws1[k][c] = W1[kb+k][c]
            int kr = t >> 2;           // 0..63
            int cq = (t & 3) * 32;
#pragma unroll
            for (int i = 0; i < 8; ++i) {
                f32x4 v = *(const f32x4*)&W1[(size_t)(kb + kr) * OUTF + cq + i * 4];
                *(f32x4*)&ws1[kr][cq + i * 4] = v;
            }
        }
        __syncthreads();
        for (int kk = 0; kk < 64; ++kk) {
            f32x4 xa = *(const f32x4*)&xsT[kk][tr * 4];
            f32x4 wb = *(const f32x4*)&ws1[kk][tc * 4];
#pragma unroll
            for (int i = 0; i < 4; ++i)
#pragma unroll
                for (int j = 0; j < 4; ++j)
                    acc[i][j] += xa[i] * wb[j];
        }
        __syncthreads();
    }

#pragma unroll
    for (int i = 0; i < 4; ++i)
        *(f32x4*)&wh[tr * 4 + i][tc * 4] = acc[i];
    __syncthreads();

    if (t < 32) {
        float s1 = 0.f, s2 = 0.f;
        for (int c = 0; c < OUTF; ++c) {
            float v = wh[t][c];
            s1 += v * a[c];
            s2 += v * a[OUTF + c];
        }
        float fsv = s1 + b_att[0];
        int r = rbase + t;
        fsb[r] = fsv;
        E1[r] = expf(fsv);
        E2[r] = expf(LRALPHA * fsv);
        fd[r] = s2;
        F1[r] = expf(s2);
        F2[r] = expf(LRALPHA * s2);
    }

    {   // WhbT[c][node] = bf16(Wh[node][c])
        int c = t >> 1;
        int rr = (t & 1) * 16;
        bf16x8 b0, b1v;
#pragma unroll
        for (int i = 0; i < 8; ++i) b0[i] = (bf16)wh[rr + i][c];
#pragma unroll
        for (int i = 0; i < 8; ++i) b1v[i] = (bf16)wh[rr + 8 + i][c];
        *(bf16x8*)&WhbT[(size_t)c * NODES + rbase + rr] = b0;
        *(bf16x8*)&WhbT[(size_t)c * NODES + rbase + rr + 8] = b1v;
    }
}

// ---------------- Kernel 2: fused masked softmax + PV (bf16 MFMA) + elu ----------------
// 1024 thr = 16 waves = 4 jgroups x 4 t-tiles. Block owns 32 rows; jgroup owns 2048 cols.
// All per-phase VMEM is register-prefetched (adj depth-2, WhbT depth-1); F1/F2 column
// tables live in LDS. Only LDS w-tile crosses the (lgkm-only) barrier each phase, so
// the compiler emits counted vmcnt waits and global loads stay in flight across phases.
#define SOFT_BAR() do { asm volatile("s_waitcnt lgkmcnt(0)" ::: "memory"); \
                        __builtin_amdgcn_s_barrier(); } while (0)

// LDS layout (dynamic, bytes):
//   [0, 32768)          8 w-buffers (4 jgroups x 2) x 4KB, XOR-swizzled
//   [32768, 33280)      denred[4][32] f32
//   [33280, 66048)      F1tab[8192] f32
//   [66048, 98816)      F2tab[8192] f32
//   epilogue acc zones (12 x 4KB = 48KB) alias [33280, 82432) — tables dead by then
#define WBUF_OFF   0
#define DENRED_OFF 32768
#define F1T_OFF    33280
#define F2T_OFF    66048
#define ZONE_OFF   33280
#define SMEM2_SIZE 98816

__global__ __launch_bounds__(1024, 4) void gat_attn_r3(
    const int* __restrict__ adj,
    const bf16* __restrict__ WhbT,
    const float* __restrict__ fsb, const float* __restrict__ E1,
    const float* __restrict__ E2,
    const float* __restrict__ F1, const float* __restrict__ F2,
    float* __restrict__ out)
{
    extern __shared__ char smem[];
    const int tid = threadIdx.x;
    const int lane = tid & 63;
    const int wv = tid >> 6;       // 0..15
    const int jg = wv >> 2;        // 0..3 : column group
    const int tt = wv & 3;         // 0..3 : output col tile / weight row group
    const int rbase = blockIdx.x * 32;

    char* wbufA = smem + WBUF_OFF + (jg * 2) * 4096;
    char* wbufB = smem + WBUF_OFF + (jg * 2 + 1) * 4096;
    float* denred = (float*)(smem + DENRED_OFF);
    float* F1t = (float*)(smem + F1T_OFF);
    float* F2t = (float*)(smem + F2T_OFF);

    // ---- stage F1/F2 column tables into LDS (once) ----
#pragma unroll
    for (int it = 0; it < 2; ++it) {
        int i = (it * 1024 + tid) * 4;
        *(f32x4*)&F1t[i] = *(const f32x4*)&F1[i];
        *(f32x4*)&F2t[i] = *(const f32x4*)&F2[i];
    }

    const int r8 = lane >> 3;          // 0..7
    const int c8 = lane & 7;           // 0..7
    const int wrow = tt * 8 + r8;      // 0..31 : weight row this lane computes
    const int arow = lane & 31;        // MFMA A-row / B-col / D-col
    const int ag = lane >> 5;          // 0..1  : k lane-group

    const int gr = rbase + wrow;
    const float fsbv = fsb[gr];
    const float e1v = E1[gr];
    const float e2v = E2[gr];

    f32x16 acc;
#pragma unroll
    for (int i = 0; i < 16; ++i) acc[i] = 0.f;
    float den = 0.f;

    const int jw0 = jg * (NODES / 4);
    const size_t adj_row = (size_t)gr * NODES;
    const size_t whb_row = (size_t)(32 * tt + arow) * NODES;

    __syncthreads();   // tables staged

    // weights for columns [jb, jb+64) -> bf16 tile row wrow in buf (XOR-swizzled)
    auto compute_w = [&](char* buf, int jb, i32x4 a0, i32x4 a1) {
        const int cb = jb + c8 * 8;
        f32x4 g10 = *(const f32x4*)&F1t[cb];
        f32x4 g11 = *(const f32x4*)&F1t[cb + 4];
        f32x4 g20 = *(const f32x4*)&F2t[cb];
        f32x4 g21 = *(const f32x4*)&F2t[cb + 4];
        bf16x8 wb;
#pragma unroll
        for (int jj = 0; jj < 4; ++jj) {
            float t = e1v * g10[jj];                 // t = e^{s};  s>0  <=>  t>1
            float w = t > 1.f ? t : e2v * g20[jj];
            w = a0[jj] ? w : 0.f;
            den += w;
            wb[jj] = (bf16)w;
        }
#pragma unroll
        for (int jj = 0; jj < 4; ++jj) {
            float t = e1v * g11[jj];
            float w = t > 1.f ? t : e2v * g21[jj];
            w = a1[jj] ? w : 0.f;
            den += w;
            wb[4 + jj] = (bf16)w;
        }
        const int off = (wrow * 128 + c8 * 16) ^ ((wrow & 7) << 4);
        *(bf16x8*)(buf + off) = wb;
    };

    // ---- prologue: phase-0 weights into bufA; whb(0) + adj(1) in flight ----
    i32x4 a0 = *(const i32x4*)&adj[adj_row + jw0 + c8 * 8];
    i32x4 a1 = *(const i32x4*)&adj[adj_row + jw0 + c8 * 8 + 4];
    i32x4 b0 = *(const i32x4*)&adj[adj_row + jw0 + 64 + c8 * 8];
    i32x4 b1 = *(const i32x4*)&adj[adj_row + jw0 + 64 + c8 * 8 + 4];
    bf16x8 wc0 = *(const bf16x8*)&WhbT[whb_row + jw0 + 0 + 8 * ag];
    bf16x8 wc1 = *(const bf16x8*)&WhbT[whb_row + jw0 + 16 + 8 * ag];
    bf16x8 wc2 = *(const bf16x8*)&WhbT[whb_row + jw0 + 32 + 8 * ag];
    bf16x8 wc3 = *(const bf16x8*)&WhbT[whb_row + jw0 + 48 + 8 * ag];
    compute_w(wbufA, jw0, a0, a1);
    SOFT_BAR();

    char* cur = wbufA;
    char* nxt = wbufB;
#pragma unroll 2
    for (int p = 0; p < 32; ++p) {
        const int jb = jw0 + p * 64;
        const int pc = (p + 2 <= 31) ? (p + 2) : 31;   // adj depth-2 prefetch (clamped)
        const int pw = (p + 1 <= 31) ? (p + 1) : 31;   // whb depth-1 prefetch (clamped)
        i32x4 n0 = *(const i32x4*)&adj[adj_row + jw0 + pc * 64 + c8 * 8];
        i32x4 n1 = *(const i32x4*)&adj[adj_row + jw0 + pc * 64 + c8 * 8 + 4];
        bf16x8 wn0 = *(const bf16x8*)&WhbT[whb_row + jw0 + pw * 64 + 0 + 8 * ag];
        bf16x8 wn1 = *(const bf16x8*)&WhbT[whb_row + jw0 + pw * 64 + 16 + 8 * ag];
        bf16x8 wn2 = *(const bf16x8*)&WhbT[whb_row + jw0 + pw * 64 + 32 + 8 * ag];
        bf16x8 wn3 = *(const bf16x8*)&WhbT[whb_row + jw0 + pw * 64 + 48 + 8 * ag];

        if (p < 31) compute_w(nxt, jb + 64, b0, b1);   // weights for next phase

        {   // MFMA on current buffer with register B-fragments
            bf16x8 af0, af1, af2, af3;
            {
                const int o0 = (arow * 128 + 0 * 32 + ag * 16) ^ ((arow & 7) << 4);
                const int o1 = (arow * 128 + 1 * 32 + ag * 16) ^ ((arow & 7) << 4);
                const int o2 = (arow * 128 + 2 * 32 + ag * 16) ^ ((arow & 7) << 4);
                const int o3 = (arow * 128 + 3 * 32 + ag * 16) ^ ((arow & 7) << 4);
                af0 = *(const bf16x8*)(cur + o0);
                af1 = *(const bf16x8*)(cur + o1);
                af2 = *(const bf16x8*)(cur + o2);
                af3 = *(const bf16x8*)(cur + o3);
            }
            acc = __builtin_amdgcn_mfma_f32_32x32x16_bf16(af0, wc0, acc, 0, 0, 0);
            acc = __builtin_amdgcn_mfma_f32_32x32x16_bf16(af1, wc1, acc, 0, 0, 0);
            acc = __builtin_amdgcn_mfma_f32_32x32x16_bf16(af2, wc2, acc, 0, 0, 0);
            acc = __builtin_amdgcn_mfma_f32_32x32x16_bf16(af3, wc3, acc, 0, 0, 0);
        }
        SOFT_BAR();
        b0 = n0; b1 = n1;
        wc0 = wn0; wc1 = wn1; wc2 = wn2; wc3 = wn3;
        char* tmp = cur; cur = nxt; nxt = tmp;
    }

    // den: reduce over the 8 column-lanes (bits 0..2)
    den += __shfl_xor(den, 1);
    den += __shfl_xor(den, 2);
    den += __shfl_xor(den, 4);
    if (c8 == 0) denred[jg * 32 + wrow] = den;

    // partial acc tiles from jgroups 1..3 -> LDS zones (alias table region, dead now)
    if (jg > 0) {
        float* z = (float*)(smem + ZONE_OFF + (size_t)((jg - 1) * 4 + tt) * 4096) + lane * 16;
        *(f32x16*)z = acc;
    }
    __syncthreads();

    if (jg == 0) {
#pragma unroll
        for (int q = 0; q < 3; ++q) {
            const float* z = (const float*)(smem + ZONE_OFF + (size_t)(q * 4 + tt) * 4096) + lane * 16;
            f32x16 v = *(const f32x16*)z;
#pragma unroll
            for (int i = 0; i < 16; ++i) acc[i] += v[i];
        }
#pragma unroll
        for (int rg = 0; rg < 16; ++rg) {
            const int row = (rg & 3) + 8 * (rg >> 2) + 4 * ag;  // verified C/D mapping
            float ds = denred[row] + denred[32 + row] + denred[64 + row] + denred[96 + row];
            float v = acc[rg] / ds;
            v = v > 0.f ? v : expm1f(v);
            out[(size_t)(rbase + row) * OUTF + 32 * tt + arow] = v;
        }
    }
}

extern "C" void kernel_launch(void* const* d_in, const int* in_sizes, int n_in,
                              void* d_out, int out_size, void* d_ws, size_t ws_size,
                              hipStream_t stream) {
    const float* x     = (const float*)d_in[0];
    const int*   adj   = (const int*)d_in[1];
    const float* W1    = (const float*)d_in[2];
    const float* b1    = (const float*)d_in[3];
    const float* a     = (const float*)d_in[4];
    const float* b_att = (const float*)d_in[5];
    float* out = (float*)d_out;

    char* ws = (char*)d_ws;
    bf16* WhbT = (bf16*)ws;                                   // 2 MB
    float* fsb = (float*)(ws + (size_t)2 * 1024 * 1024);
    float* E1 = fsb + NODES;
    float* E2 = E1 + NODES;
    float* fd = E2 + NODES;
    float* F1 = fd + NODES;
    float* F2 = F1 + NODES;

    hipLaunchKernelGGL(gat_prep_r3, dim3(NODES / 32), dim3(256), 0, stream,
                       x, W1, b1, a, b_att, WhbT, fsb, E1, E2, fd, F1, F2);

    hipLaunchKernelGGL(gat_attn_r3, dim3(NODES / 32), dim3(1024), SMEM2_SIZE, stream,
                       adj, WhbT, fsb, E1, E2, F1, F2, out);
}